// Round 5
// baseline (11779.256 us; speedup 1.0000x reference)
//
#include <hip/hip_runtime.h>

#define L 6
#define D 1024
#define DFF 4096
#define BATCH 4
#define S 1024

typedef __attribute__((ext_vector_type(4))) float f32x4;
typedef __attribute__((ext_vector_type(8))) short short8;

__device__ __forceinline__ ushort f2bf(float f) {
    unsigned int u = __float_as_uint(f);
    u = u + 0x7FFF + ((u >> 16) & 1);
    return (ushort)(u >> 16);
}
__device__ __forceinline__ float bf2f(ushort u) {
    return __uint_as_float(((unsigned int)u) << 16);
}

// ---------------- split f32 -> (hi, lo) bf16 ----------------
__global__ __launch_bounds__(256) void cvt_split(const float* __restrict__ in,
                                                 ushort* __restrict__ oh,
                                                 ushort* __restrict__ ol, int n) {
    int i = (blockIdx.x * 256 + threadIdx.x) * 4;
    if (i >= n) return;
    float4 v = *(const float4*)&in[i];
    ushort4 h, l;
    h.x = f2bf(v.x); l.x = f2bf(v.x - bf2f(h.x));
    h.y = f2bf(v.y); l.y = f2bf(v.y - bf2f(h.y));
    h.z = f2bf(v.z); l.z = f2bf(v.z - bf2f(h.z));
    h.w = f2bf(v.w); l.w = f2bf(v.w - bf2f(h.w));
    *(ushort4*)&oh[i] = h;
    *(ushort4*)&ol[i] = l;
}

// ---------------- transpose weight [K,N] f32 -> [N,K] (hi,lo) bf16 ----------------
__global__ __launch_bounds__(256) void transpose_w(const float* __restrict__ W,
                                                   ushort* __restrict__ Wth,
                                                   ushort* __restrict__ Wtl,
                                                   int K, int N) {
    __shared__ float T[32][33];
    int n0 = blockIdx.x * 32, k0 = blockIdx.y * 32;
    int t = threadIdx.x;
    int r = t >> 3, c4 = (t & 7) * 4;
    float4 v = *(const float4*)&W[(size_t)(k0 + r) * N + n0 + c4];
    T[r][c4 + 0] = v.x; T[r][c4 + 1] = v.y; T[r][c4 + 2] = v.z; T[r][c4 + 3] = v.w;
    __syncthreads();
    ushort4 h, l;
    float a0 = T[c4 + 0][r], a1 = T[c4 + 1][r], a2 = T[c4 + 2][r], a3 = T[c4 + 3][r];
    h.x = f2bf(a0); l.x = f2bf(a0 - bf2f(h.x));
    h.y = f2bf(a1); l.y = f2bf(a1 - bf2f(h.y));
    h.z = f2bf(a2); l.z = f2bf(a2 - bf2f(h.z));
    h.w = f2bf(a3); l.w = f2bf(a3 - bf2f(h.w));
    size_t idx = (size_t)(n0 + r) * K + k0 + c4;
    *(ushort4*)&Wth[idx] = h;
    *(ushort4*)&Wtl[idx] = l;
}

// ---------------- split-precision batched GEMM ----------------
// C = alpha * (Ah+Al)[M,K] @ (Bh+Bl)[N,K]^T (+bias), via ah*bh + ah*bl + al*bh
// outputs: optional f32 Cf; optional (Ch, Cl) split pair; transC stores pair as [b][n][s]
__global__ __launch_bounds__(256) void gemm_sp(
    const ushort* __restrict__ Ah, const ushort* __restrict__ Al,
    const ushort* __restrict__ Bh, const ushort* __restrict__ Bl,
    float* __restrict__ Cf, ushort* __restrict__ Ch, ushort* __restrict__ Cl,
    const float* __restrict__ bias, float alpha,
    int M, int N, int K, long sA, long sB, long sC, int transC) {
    __shared__ ushort Ash[128][72];
    __shared__ ushort Asl[128][72];
    __shared__ ushort Bsh[128][72];
    __shared__ ushort Bsl[128][72];
    const int z = blockIdx.z;
    Ah += (size_t)z * sA; Al += (size_t)z * sA;
    Bh += (size_t)z * sB; Bl += (size_t)z * sB;
    const size_t coff = (size_t)z * sC;
    const int bm = blockIdx.y * 128, bn = blockIdx.x * 128;
    const int tid = threadIdx.x, lane = tid & 63, wid = tid >> 6;
    const int wr = wid >> 1, wc = wid & 1;
    const int lr = lane & 15, lg = lane >> 4;
    f32x4 acc[4][4] = {};

    int srow[4], scol[4];
#pragma unroll
    for (int c = 0; c < 4; c++) {
        int ch = c * 256 + tid;
        srow[c] = ch >> 3;
        scol[c] = (ch & 7) * 8;
    }

    const int NT = K >> 6;
    uint4 rah[4], ral[4], rbh[4], rbl[4];
#pragma unroll
    for (int c = 0; c < 4; c++) {
        size_t ao = (size_t)(bm + srow[c]) * K + scol[c];
        size_t bo = (size_t)(bn + srow[c]) * K + scol[c];
        rah[c] = *(const uint4*)(Ah + ao);
        ral[c] = *(const uint4*)(Al + ao);
        rbh[c] = *(const uint4*)(Bh + bo);
        rbl[c] = *(const uint4*)(Bl + bo);
    }
    for (int kt = 0; kt < NT; kt++) {
        __syncthreads();
#pragma unroll
        for (int c = 0; c < 4; c++) {
            *(uint4*)&Ash[srow[c]][scol[c]] = rah[c];
            *(uint4*)&Asl[srow[c]][scol[c]] = ral[c];
            *(uint4*)&Bsh[srow[c]][scol[c]] = rbh[c];
            *(uint4*)&Bsl[srow[c]][scol[c]] = rbl[c];
        }
        __syncthreads();
        if (kt + 1 < NT) {
            int k0 = (kt + 1) << 6;
#pragma unroll
            for (int c = 0; c < 4; c++) {
                size_t ao = (size_t)(bm + srow[c]) * K + k0 + scol[c];
                size_t bo = (size_t)(bn + srow[c]) * K + k0 + scol[c];
                rah[c] = *(const uint4*)(Ah + ao);
                ral[c] = *(const uint4*)(Al + ao);
                rbh[c] = *(const uint4*)(Bh + bo);
                rbl[c] = *(const uint4*)(Bl + bo);
            }
        }
#pragma unroll
        for (int ks = 0; ks < 2; ks++) {
            short8 afh[4], afl[4], bfh[4], bfl[4];
#pragma unroll
            for (int i = 0; i < 4; i++) {
                afh[i] = *(const short8*)&Ash[wr * 64 + i * 16 + lr][ks * 32 + lg * 8];
                afl[i] = *(const short8*)&Asl[wr * 64 + i * 16 + lr][ks * 32 + lg * 8];
                bfh[i] = *(const short8*)&Bsh[wc * 64 + i * 16 + lr][ks * 32 + lg * 8];
                bfl[i] = *(const short8*)&Bsl[wc * 64 + i * 16 + lr][ks * 32 + lg * 8];
            }
#pragma unroll
            for (int i = 0; i < 4; i++)
#pragma unroll
                for (int j = 0; j < 4; j++) {
                    acc[i][j] = __builtin_amdgcn_mfma_f32_16x16x32_bf16(afh[i], bfh[j], acc[i][j], 0, 0, 0);
                    acc[i][j] = __builtin_amdgcn_mfma_f32_16x16x32_bf16(afh[i], bfl[j], acc[i][j], 0, 0, 0);
                    acc[i][j] = __builtin_amdgcn_mfma_f32_16x16x32_bf16(afl[i], bfh[j], acc[i][j], 0, 0, 0);
                }
        }
    }
#pragma unroll
    for (int i = 0; i < 4; i++) {
#pragma unroll
        for (int j = 0; j < 4; j++) {
#pragma unroll
            for (int r = 0; r < 4; r++) {
                int m = bm + wr * 64 + i * 16 + lg * 4 + r;
                int n = bn + wc * 64 + j * 16 + lr;
                float v = acc[i][j][r] * alpha;
                if (bias) v += bias[n];
                if (Cf) Cf[coff + (size_t)m * N + n] = v;
                if (Ch) {
                    size_t idx = transC ? ((size_t)(m >> 10) * 1048576 + (size_t)n * 1024 + (size_t)(m & 1023))
                                        : (coff + (size_t)m * N + n);
                    ushort h = f2bf(v);
                    Ch[idx] = h;
                    Cl[idx] = f2bf(v - bf2f(h));
                }
            }
        }
    }
}

// ---------------- row softmax (f32 in, split bf16 out) ----------------
__global__ __launch_bounds__(256) void softmax_rows(const float* __restrict__ Sc,
                                                    ushort* __restrict__ Ph,
                                                    ushort* __restrict__ Pl, int causal) {
    __shared__ float red[4];
    int q = blockIdx.x, b = blockIdx.y;
    size_t base = ((size_t)b * S + q) * S;
    int valid = causal ? (q + 1) : S;
    int tid = threadIdx.x;
    float v[4];
    float mx = -3e38f;
#pragma unroll
    for (int j = 0; j < 4; j++) {
        int c = tid + j * 256;
        float x = Sc[base + c];
        v[j] = (c < valid) ? x : -3e38f;
        mx = fmaxf(mx, v[j]);
    }
    for (int o = 32; o; o >>= 1) mx = fmaxf(mx, __shfl_xor(mx, o));
    if ((tid & 63) == 0) red[tid >> 6] = mx;
    __syncthreads();
    mx = fmaxf(fmaxf(red[0], red[1]), fmaxf(red[2], red[3]));
    float s = 0.f;
#pragma unroll
    for (int j = 0; j < 4; j++) {
        int c = tid + j * 256;
        float e = (c < valid) ? __expf(v[j] - mx) : 0.f;
        v[j] = e;
        s += e;
    }
    for (int o = 32; o; o >>= 1) s += __shfl_xor(s, o);
    __syncthreads();
    if ((tid & 63) == 0) red[tid >> 6] = s;
    __syncthreads();
    s = red[0] + red[1] + red[2] + red[3];
    float inv = 1.0f / s;
#pragma unroll
    for (int j = 0; j < 4; j++) {
        int c = tid + j * 256;
        float p = v[j] * inv;
        ushort h = f2bf(p);
        Ph[base + c] = h;
        Pl[base + c] = f2bf(p - bf2f(h));
    }
}

// ---------------- residual + layernorm (f32 in/out + split bf16 out) ----------------
__global__ __launch_bounds__(256) void ln_res(const float* __restrict__ xin,
                                              const float* __restrict__ y,
                                              const float* __restrict__ g,
                                              const float* __restrict__ bta,
                                              float* __restrict__ xof,
                                              ushort* __restrict__ xh,
                                              ushort* __restrict__ xl) {
    __shared__ float red[4];
    int row = blockIdx.x;
    size_t base = (size_t)row * D;
    int tid = threadIdx.x;
    int c0 = tid * 4;
    float4 xv = *(const float4*)&xin[base + c0];
    float4 yv = *(const float4*)&y[base + c0];
    float t[4] = {xv.x + yv.x, xv.y + yv.y, xv.z + yv.z, xv.w + yv.w};
    float s = t[0] + t[1] + t[2] + t[3];
    for (int o = 32; o; o >>= 1) s += __shfl_xor(s, o);
    if ((tid & 63) == 0) red[tid >> 6] = s;
    __syncthreads();
    s = red[0] + red[1] + red[2] + red[3];
    float mean = s * (1.0f / D);
    float vs = 0.f;
#pragma unroll
    for (int j = 0; j < 4; j++) {
        float dd = t[j] - mean;
        vs += dd * dd;
    }
    for (int o = 32; o; o >>= 1) vs += __shfl_xor(vs, o);
    __syncthreads();
    if ((tid & 63) == 0) red[tid >> 6] = vs;
    __syncthreads();
    vs = red[0] + red[1] + red[2] + red[3];
    float inv = rsqrtf(vs * (1.0f / D) + 1e-5f);
    float4 gv = *(const float4*)&g[c0];
    float4 bv = *(const float4*)&bta[c0];
    float o0 = (t[0] - mean) * inv * gv.x + bv.x;
    float o1 = (t[1] - mean) * inv * gv.y + bv.y;
    float o2 = (t[2] - mean) * inv * gv.z + bv.z;
    float o3 = (t[3] - mean) * inv * gv.w + bv.w;
    float4 fo = {o0, o1, o2, o3};
    *(float4*)&xof[base + c0] = fo;
    ushort4 h, l;
    h.x = f2bf(o0); l.x = f2bf(o0 - bf2f(h.x));
    h.y = f2bf(o1); l.y = f2bf(o1 - bf2f(h.y));
    h.z = f2bf(o2); l.z = f2bf(o2 - bf2f(h.z));
    h.w = f2bf(o3); l.w = f2bf(o3 - bf2f(h.w));
    *(ushort4*)&xh[base + c0] = h;
    *(ushort4*)&xl[base + c0] = l;
}

// ---------------- guard fill (f32 output) ----------------
__global__ __launch_bounds__(256) void fill_f32(float* out, float v, int n) {
    int i = (blockIdx.x * 256 + threadIdx.x) * 4;
    if (i >= n) return;
    float4 f = {v, v, v, v};
    *(float4*)&out[i] = f;
}

extern "C" void kernel_launch(void* const* d_in, const int* in_sizes, int n_in,
                              void* d_out, int out_size, void* d_ws, size_t ws_size,
                              hipStream_t stream) {
    dim3 blk(256);
    const int M = BATCH * S;  // 4096
    const int fill_blocks = (out_size / 4 + 255) / 256;

    // weights are the LAST 18 entries
    int base = n_in - 18;
    bool layout_ok = (base >= 2) && (out_size == M * D) &&
                     (in_sizes[0] == M * D) && (in_sizes[1] == M * D) &&
                     (in_sizes[base] == L * D * D) && (in_sizes[base + 4] == L * D) &&
                     (in_sizes[base + 12] == L * D * DFF) && (in_sizes[base + 13] == L * DFF);
    if (!layout_ok) {
        fill_f32<<<fill_blocks, blk, 0, stream>>>((float*)d_out, 9000.f, out_size);
        return;
    }
    const float* x_in = (const float*)d_in[0];
    const float* enc  = (const float*)d_in[1];
    const float* Wq1 = (const float*)d_in[base + 0];
    const float* Wk1 = (const float*)d_in[base + 1];
    const float* Wv1 = (const float*)d_in[base + 2];
    const float* Wo1 = (const float*)d_in[base + 3];
    const float* g1  = (const float*)d_in[base + 4];
    const float* b1  = (const float*)d_in[base + 5];
    const float* Wq2 = (const float*)d_in[base + 6];
    const float* Wk2 = (const float*)d_in[base + 7];
    const float* Wv2 = (const float*)d_in[base + 8];
    const float* Wo2 = (const float*)d_in[base + 9];
    const float* g2  = (const float*)d_in[base + 10];
    const float* b2  = (const float*)d_in[base + 11];
    const float* Wf1 = (const float*)d_in[base + 12];
    const float* bf1 = (const float*)d_in[base + 13];
    const float* Wf2 = (const float*)d_in[base + 14];
    const float* bf2 = (const float*)d_in[base + 15];
    const float* g3  = (const float*)d_in[base + 16];
    const float* b3  = (const float*)d_in[base + 17];

    const size_t PL = (size_t)M * D * 2;   // one bf16 plane: 8 MiB
    const size_t F32 = (size_t)M * D * 4;  // f32 plane: 16 MiB
    const size_t CLU = 8 * PL;             // cluster: 64 MiB (hb pair / attn bufs)
    const size_t required = F32 + 2 * PL            /* xf, xh, xl */
                          + 2 * PL                  /* eh, el */
                          + 6 * PL                  /* q,k,vt pairs */
                          + F32                     /* yf */
                          + CLU                     /* hb pair | att pair+scores+p pair */
                          + 2 * PL + 4096;          /* wt pair */
    if (ws_size < required) {
        fill_f32<<<fill_blocks, blk, 0, stream>>>((float*)d_out, 500.f, out_size);
        return;
    }

    char* ws = (char*)d_ws;
    size_t off = 0;
    auto carve = [&](size_t bytes) -> char* {
        char* p = ws + off;
        off += (bytes + 255) & ~(size_t)255;
        return p;
    };
    float*  xf  = (float*)carve(F32);
    ushort* xh  = (ushort*)carve(PL);
    ushort* xl  = (ushort*)carve(PL);
    ushort* eh  = (ushort*)carve(PL);
    ushort* el  = (ushort*)carve(PL);
    ushort* qh  = (ushort*)carve(PL);
    ushort* ql  = (ushort*)carve(PL);
    ushort* kh  = (ushort*)carve(PL);
    ushort* kl  = (ushort*)carve(PL);
    ushort* vth = (ushort*)carve(PL);
    ushort* vtl = (ushort*)carve(PL);
    float*  yf  = (float*)carve(F32);
    char*   clu = carve(CLU);
    ushort* hbh = (ushort*)clu;                   // 32 MiB
    ushort* hbl = (ushort*)(clu + 4 * PL);        // 32 MiB
    ushort* ath = (ushort*)clu;                   // 8 MiB
    ushort* atl = (ushort*)(clu + PL);            // 8 MiB
    float*  scores = (float*)(clu + 2 * PL);      // 16 MiB
    ushort* ph  = (ushort*)(clu + 4 * PL);        // 8 MiB
    ushort* pl  = (ushort*)(clu + 5 * PL);        // 8 MiB
    ushort* wth = (ushort*)carve(PL);
    ushort* wtl = (ushort*)carve(PL);

    auto gemm = [&](const ushort* Ah_, const ushort* Al_, const ushort* Bh_, const ushort* Bl_,
                    float* Cf, ushort* Ch, ushort* Cl, const float* bias, float alpha,
                    int gm, int gn, int gk, long sA, long sB, long sC, int transC, int batch) {
        dim3 g(gn / 128, gm / 128, batch);
        gemm_sp<<<g, blk, 0, stream>>>(Ah_, Al_, Bh_, Bl_, Cf, Ch, Cl, bias, alpha,
                                       gm, gn, gk, sA, sB, sC, transC);
    };
    auto transp = [&](const float* W, int K, int N) {
        transpose_w<<<dim3(N / 32, K / 32), blk, 0, stream>>>(W, wth, wtl, K, N);
    };

    cvt_split<<<(M * D) / 1024, blk, 0, stream>>>(x_in, xh, xl, M * D);
    cvt_split<<<(M * D) / 1024, blk, 0, stream>>>(enc, eh, el, M * D);

    const long SM = (long)S * S;
    const long SD = (long)S * D;

    for (int i = 0; i < L; i++) {
        // ---- self-attention (causal) ----
        transp(Wq1 + (size_t)i * D * D, D, D);
        gemm(xh, xl, wth, wtl, nullptr, qh, ql, nullptr, 1.f, M, D, D, 0, 0, 0, 0, 1);
        transp(Wk1 + (size_t)i * D * D, D, D);
        gemm(xh, xl, wth, wtl, nullptr, kh, kl, nullptr, 1.f, M, D, D, 0, 0, 0, 0, 1);
        transp(Wv1 + (size_t)i * D * D, D, D);
        gemm(xh, xl, wth, wtl, nullptr, vth, vtl, nullptr, 1.f, M, D, D, 0, 0, 0, 1, 1);
        gemm(qh, ql, kh, kl, scores, nullptr, nullptr, nullptr, 0.125f, S, S, D, SD, SD, SM, 0, BATCH);
        softmax_rows<<<dim3(S, BATCH), blk, 0, stream>>>(scores, ph, pl, 1);
        gemm(ph, pl, vth, vtl, nullptr, ath, atl, nullptr, 1.f, S, D, S, SM, SD, SD, 0, BATCH);
        transp(Wo1 + (size_t)i * D * D, D, D);
        gemm(ath, atl, wth, wtl, yf, nullptr, nullptr, nullptr, 1.f, M, D, D, 0, 0, 0, 0, 1);
        ln_res<<<M, blk, 0, stream>>>((i == 0) ? x_in : xf, yf,
                                      g1 + (size_t)i * D, b1 + (size_t)i * D, xf, xh, xl);

        // ---- cross-attention (all visible) ----
        transp(Wq2 + (size_t)i * D * D, D, D);
        gemm(xh, xl, wth, wtl, nullptr, qh, ql, nullptr, 1.f, M, D, D, 0, 0, 0, 0, 1);
        transp(Wk2 + (size_t)i * D * D, D, D);
        gemm(eh, el, wth, wtl, nullptr, kh, kl, nullptr, 1.f, M, D, D, 0, 0, 0, 0, 1);
        transp(Wv2 + (size_t)i * D * D, D, D);
        gemm(eh, el, wth, wtl, nullptr, vth, vtl, nullptr, 1.f, M, D, D, 0, 0, 0, 1, 1);
        gemm(qh, ql, kh, kl, scores, nullptr, nullptr, nullptr, 0.125f, S, S, D, SD, SD, SM, 0, BATCH);
        softmax_rows<<<dim3(S, BATCH), blk, 0, stream>>>(scores, ph, pl, 0);
        gemm(ph, pl, vth, vtl, nullptr, ath, atl, nullptr, 1.f, S, D, S, SM, SD, SD, 0, BATCH);
        transp(Wo2 + (size_t)i * D * D, D, D);
        gemm(ath, atl, wth, wtl, yf, nullptr, nullptr, nullptr, 1.f, M, D, D, 0, 0, 0, 0, 1);
        ln_res<<<M, blk, 0, stream>>>(xf, yf, g2 + (size_t)i * D, b2 + (size_t)i * D, xf, xh, xl);

        // ---- feedforward ----
        transp(Wf1 + (size_t)i * D * DFF, D, DFF);
        gemm(xh, xl, wth, wtl, nullptr, hbh, hbl, bf1 + (size_t)i * DFF, 1.f, M, DFF, D, 0, 0, 0, 0, 1);
        transp(Wf2 + (size_t)i * DFF * D, DFF, D);
        gemm(hbh, hbl, wth, wtl, yf, nullptr, nullptr, bf2 + (size_t)i * D, 1.f, M, D, DFF, 0, 0, 0, 0, 1);
        float* lnout = (i == L - 1) ? (float*)d_out : xf;
        ln_res<<<M, blk, 0, stream>>>(xf, yf, g3 + (size_t)i * D, b3 + (size_t)i * D, lnout, xh, xl);
    }
}

// Round 6
// 5093.929 us; speedup vs baseline: 2.3124x; 2.3124x over previous
//
#include <hip/hip_runtime.h>

#define L 6
#define D 1024
#define DFF 4096
#define BATCH 4
#define S 1024

typedef __attribute__((ext_vector_type(4))) float f32x4;
typedef __attribute__((ext_vector_type(8))) short short8;

__device__ __forceinline__ ushort f2bf(float f) {
    unsigned int u = __float_as_uint(f);
    u = u + 0x7FFF + ((u >> 16) & 1);
    return (ushort)(u >> 16);
}
__device__ __forceinline__ float bf2f(ushort u) {
    return __uint_as_float(((unsigned int)u) << 16);
}
// pack value as (lo16=hi-part, hi16=lo-part) u32
__device__ __forceinline__ uint packhl(float v) {
    ushort h = f2bf(v);
    ushort l = f2bf(v - bf2f(h));
    return (uint)h | ((uint)l << 16);
}
__device__ __forceinline__ void unpack4(uint4 p, ushort4& h, ushort4& l) {
    h.x = (ushort)(p.x & 0xffff); l.x = (ushort)(p.x >> 16);
    h.y = (ushort)(p.y & 0xffff); l.y = (ushort)(p.y >> 16);
    h.z = (ushort)(p.z & 0xffff); l.z = (ushort)(p.z >> 16);
    h.w = (ushort)(p.w & 0xffff); l.w = (ushort)(p.w >> 16);
}

// ---------------- f32 -> packed split ----------------
__global__ __launch_bounds__(256) void cvt_pack(const float* __restrict__ in,
                                                uint* __restrict__ op, int n) {
    int i = (blockIdx.x * 256 + threadIdx.x) * 4;
    if (i >= n) return;
    float4 v = *(const float4*)&in[i];
    uint4 o = {packhl(v.x), packhl(v.y), packhl(v.z), packhl(v.w)};
    *(uint4*)&op[i] = o;
}

// ---------------- transpose weight [K,N] f32 -> [N,K] packed ----------------
__global__ __launch_bounds__(256) void transpose_w(const float* __restrict__ W,
                                                   uint* __restrict__ Wtp,
                                                   int K, int N) {
    __shared__ float T[32][33];
    int n0 = blockIdx.x * 32, k0 = blockIdx.y * 32;
    int t = threadIdx.x;
    int r = t >> 3, c4 = (t & 7) * 4;
    float4 v = *(const float4*)&W[(size_t)(k0 + r) * N + n0 + c4];
    T[r][c4 + 0] = v.x; T[r][c4 + 1] = v.y; T[r][c4 + 2] = v.z; T[r][c4 + 3] = v.w;
    __syncthreads();
    uint4 o = {packhl(T[c4 + 0][r]), packhl(T[c4 + 1][r]),
               packhl(T[c4 + 2][r]), packhl(T[c4 + 3][r])};
    *(uint4*)&Wtp[(size_t)(n0 + r) * K + k0 + c4] = o;
}

// ---------------- transpose packed V [b][s][d] -> [b][d][s] ----------------
__global__ __launch_bounds__(256) void vtrans(const uint* __restrict__ in,
                                              uint* __restrict__ out) {
    __shared__ uint T[32][33];
    int d0 = blockIdx.x * 32, s0 = blockIdx.y * 32, b = blockIdx.z;
    int t = threadIdx.x;
    int r = t >> 3, c4 = (t & 7) * 4;
    uint4 v = *(const uint4*)&in[((size_t)(b * S + s0 + r)) * D + d0 + c4];
    T[r][c4 + 0] = v.x; T[r][c4 + 1] = v.y; T[r][c4 + 2] = v.z; T[r][c4 + 3] = v.w;
    __syncthreads();
    uint4 o = {T[c4 + 0][r], T[c4 + 1][r], T[c4 + 2][r], T[c4 + 3][r]};
    *(uint4*)&out[((size_t)(b * D + d0 + r)) * S + s0 + c4] = o;
}

// ---------------- split-precision batched GEMM (packed u32 I/O) ----------------
// C = alpha * A[M,K] @ B[N,K]^T (+bias);  A,B packed (h,l); 3 MFMA passes: hh+hl+lh
__global__ __launch_bounds__(256) void gemm_sp(
    const uint* __restrict__ Ap, const uint* __restrict__ Bp,
    float* __restrict__ Cf, uint* __restrict__ Cp,
    const float* __restrict__ bias, float alpha,
    int M, int N, int K, long sA, long sB, long sC) {
    __shared__ ushort Ash[128][72];
    __shared__ ushort Asl[128][72];
    __shared__ ushort Bsh[128][72];
    __shared__ ushort Bsl[128][72];
    const int z = blockIdx.z;
    Ap += (size_t)z * sA;
    Bp += (size_t)z * sB;
    const size_t coff = (size_t)z * sC;
    const int bm = blockIdx.y * 128, bn = blockIdx.x * 128;
    const int tid = threadIdx.x, lane = tid & 63, wid = tid >> 6;
    const int wr = wid >> 1, wc = wid & 1;
    const int lr = lane & 15, lg = lane >> 4;
    f32x4 acc[4][4] = {};

    int srow[8], scol[8];
#pragma unroll
    for (int c = 0; c < 8; c++) {
        int idx = c * 256 + tid;
        srow[c] = idx >> 4;
        scol[c] = (idx & 15) * 4;
    }

    const int NT = K >> 6;
    uint4 ra[8], rb[8];
#pragma unroll
    for (int c = 0; c < 8; c++) {
        ra[c] = *(const uint4*)(Ap + (size_t)(bm + srow[c]) * K + scol[c]);
        rb[c] = *(const uint4*)(Bp + (size_t)(bn + srow[c]) * K + scol[c]);
    }
    for (int kt = 0; kt < NT; kt++) {
        __syncthreads();
#pragma unroll
        for (int c = 0; c < 8; c++) {
            ushort4 h, l;
            unpack4(ra[c], h, l);
            *(ushort4*)&Ash[srow[c]][scol[c]] = h;
            *(ushort4*)&Asl[srow[c]][scol[c]] = l;
            unpack4(rb[c], h, l);
            *(ushort4*)&Bsh[srow[c]][scol[c]] = h;
            *(ushort4*)&Bsl[srow[c]][scol[c]] = l;
        }
        __syncthreads();
        if (kt + 1 < NT) {
            int k0 = (kt + 1) << 6;
#pragma unroll
            for (int c = 0; c < 8; c++) {
                ra[c] = *(const uint4*)(Ap + (size_t)(bm + srow[c]) * K + k0 + scol[c]);
                rb[c] = *(const uint4*)(Bp + (size_t)(bn + srow[c]) * K + k0 + scol[c]);
            }
        }
#pragma unroll
        for (int ks = 0; ks < 2; ks++) {
            short8 afh[4], afl[4], bfh[4], bfl[4];
#pragma unroll
            for (int i = 0; i < 4; i++) {
                afh[i] = *(const short8*)&Ash[wr * 64 + i * 16 + lr][ks * 32 + lg * 8];
                afl[i] = *(const short8*)&Asl[wr * 64 + i * 16 + lr][ks * 32 + lg * 8];
                bfh[i] = *(const short8*)&Bsh[wc * 64 + i * 16 + lr][ks * 32 + lg * 8];
                bfl[i] = *(const short8*)&Bsl[wc * 64 + i * 16 + lr][ks * 32 + lg * 8];
            }
#pragma unroll
            for (int i = 0; i < 4; i++)
#pragma unroll
                for (int j = 0; j < 4; j++) {
                    acc[i][j] = __builtin_amdgcn_mfma_f32_16x16x32_bf16(afh[i], bfh[j], acc[i][j], 0, 0, 0);
                    acc[i][j] = __builtin_amdgcn_mfma_f32_16x16x32_bf16(afh[i], bfl[j], acc[i][j], 0, 0, 0);
                    acc[i][j] = __builtin_amdgcn_mfma_f32_16x16x32_bf16(afl[i], bfh[j], acc[i][j], 0, 0, 0);
                }
        }
    }
#pragma unroll
    for (int i = 0; i < 4; i++) {
#pragma unroll
        for (int j = 0; j < 4; j++) {
#pragma unroll
            for (int r = 0; r < 4; r++) {
                int m = bm + wr * 64 + i * 16 + lg * 4 + r;
                int n = bn + wc * 64 + j * 16 + lr;
                float v = acc[i][j][r] * alpha;
                if (bias) v += bias[n];
                if (Cf) Cf[coff + (size_t)m * N + n] = v;
                if (Cp) Cp[coff + (size_t)m * N + n] = packhl(v);
            }
        }
    }
}

// ---------------- row softmax (f32 in, packed out) ----------------
__global__ __launch_bounds__(256) void softmax_rows(const float* __restrict__ Sc,
                                                    uint* __restrict__ Pp, int causal) {
    __shared__ float red[4];
    int q = blockIdx.x, b = blockIdx.y;
    size_t base = ((size_t)b * S + q) * S;
    int valid = causal ? (q + 1) : S;
    int tid = threadIdx.x;
    float v[4];
    float mx = -3e38f;
#pragma unroll
    for (int j = 0; j < 4; j++) {
        int c = tid + j * 256;
        float x = Sc[base + c];
        v[j] = (c < valid) ? x : -3e38f;
        mx = fmaxf(mx, v[j]);
    }
    for (int o = 32; o; o >>= 1) mx = fmaxf(mx, __shfl_xor(mx, o));
    if ((tid & 63) == 0) red[tid >> 6] = mx;
    __syncthreads();
    mx = fmaxf(fmaxf(red[0], red[1]), fmaxf(red[2], red[3]));
    float s = 0.f;
#pragma unroll
    for (int j = 0; j < 4; j++) {
        int c = tid + j * 256;
        float e = (c < valid) ? __expf(v[j] - mx) : 0.f;
        v[j] = e;
        s += e;
    }
    for (int o = 32; o; o >>= 1) s += __shfl_xor(s, o);
    __syncthreads();
    if ((tid & 63) == 0) red[tid >> 6] = s;
    __syncthreads();
    s = red[0] + red[1] + red[2] + red[3];
    float inv = 1.0f / s;
#pragma unroll
    for (int j = 0; j < 4; j++) {
        int c = tid + j * 256;
        Pp[base + c] = packhl(v[j] * inv);
    }
}

// ---------------- residual + layernorm (f32 in, f32 + packed out) ----------------
__global__ __launch_bounds__(256) void ln_res(const float* __restrict__ xin,
                                              const float* __restrict__ y,
                                              const float* __restrict__ g,
                                              const float* __restrict__ bta,
                                              float* __restrict__ xof,
                                              uint* __restrict__ xp) {
    __shared__ float red[4];
    int row = blockIdx.x;
    size_t base = (size_t)row * D;
    int tid = threadIdx.x;
    int c0 = tid * 4;
    float4 xv = *(const float4*)&xin[base + c0];
    float4 yv = *(const float4*)&y[base + c0];
    float t[4] = {xv.x + yv.x, xv.y + yv.y, xv.z + yv.z, xv.w + yv.w};
    float s = t[0] + t[1] + t[2] + t[3];
    for (int o = 32; o; o >>= 1) s += __shfl_xor(s, o);
    if ((tid & 63) == 0) red[tid >> 6] = s;
    __syncthreads();
    s = red[0] + red[1] + red[2] + red[3];
    float mean = s * (1.0f / D);
    float vs = 0.f;
#pragma unroll
    for (int j = 0; j < 4; j++) {
        float dd = t[j] - mean;
        vs += dd * dd;
    }
    for (int o = 32; o; o >>= 1) vs += __shfl_xor(vs, o);
    __syncthreads();
    if ((tid & 63) == 0) red[tid >> 6] = vs;
    __syncthreads();
    vs = red[0] + red[1] + red[2] + red[3];
    float inv = rsqrtf(vs * (1.0f / D) + 1e-5f);
    float4 gv = *(const float4*)&g[c0];
    float4 bv = *(const float4*)&bta[c0];
    float o0 = (t[0] - mean) * inv * gv.x + bv.x;
    float o1 = (t[1] - mean) * inv * gv.y + bv.y;
    float o2 = (t[2] - mean) * inv * gv.z + bv.z;
    float o3 = (t[3] - mean) * inv * gv.w + bv.w;
    float4 fo = {o0, o1, o2, o3};
    *(float4*)&xof[base + c0] = fo;
    uint4 po = {packhl(o0), packhl(o1), packhl(o2), packhl(o3)};
    *(uint4*)&xp[base + c0] = po;
}

// ---------------- guard fill (f32 output) ----------------
__global__ __launch_bounds__(256) void fill_f32(float* out, float v, int n) {
    int i = (blockIdx.x * 256 + threadIdx.x) * 4;
    if (i >= n) return;
    float4 f = {v, v, v, v};
    *(float4*)&out[i] = f;
}

extern "C" void kernel_launch(void* const* d_in, const int* in_sizes, int n_in,
                              void* d_out, int out_size, void* d_ws, size_t ws_size,
                              hipStream_t stream) {
    dim3 blk(256);
    const int M = BATCH * S;  // 4096
    const int fill_blocks = (out_size / 4 + 255) / 256;

    // weights are the LAST 18 entries
    int base = n_in - 18;
    bool layout_ok = (base >= 2) && (out_size == M * D) &&
                     (in_sizes[0] == M * D) && (in_sizes[1] == M * D) &&
                     (in_sizes[base] == L * D * D) && (in_sizes[base + 4] == L * D) &&
                     (in_sizes[base + 12] == L * D * DFF) && (in_sizes[base + 13] == L * DFF);
    if (!layout_ok) {
        fill_f32<<<fill_blocks, blk, 0, stream>>>((float*)d_out, 9000.f, out_size);
        return;
    }
    const float* x_in = (const float*)d_in[0];
    const float* enc  = (const float*)d_in[1];
    const float* Wq1 = (const float*)d_in[base + 0];
    const float* Wk1 = (const float*)d_in[base + 1];
    const float* Wv1 = (const float*)d_in[base + 2];
    const float* Wo1 = (const float*)d_in[base + 3];
    const float* g1  = (const float*)d_in[base + 4];
    const float* b1  = (const float*)d_in[base + 5];
    const float* Wq2 = (const float*)d_in[base + 6];
    const float* Wk2 = (const float*)d_in[base + 7];
    const float* Wv2 = (const float*)d_in[base + 8];
    const float* Wo2 = (const float*)d_in[base + 9];
    const float* g2  = (const float*)d_in[base + 10];
    const float* b2  = (const float*)d_in[base + 11];
    const float* Wf1 = (const float*)d_in[base + 12];
    const float* bf1 = (const float*)d_in[base + 13];
    const float* Wf2 = (const float*)d_in[base + 14];
    const float* bf2 = (const float*)d_in[base + 15];
    const float* g3  = (const float*)d_in[base + 16];
    const float* b3  = (const float*)d_in[base + 17];

    const size_t PK  = (size_t)M * D * 4;   // packed / f32 plane: 16 MiB
    const size_t required = 11 * PK;        // 176 MiB
    if (ws_size < required) {
        fill_f32<<<fill_blocks, blk, 0, stream>>>((float*)d_out, 500.f, out_size);
        return;
    }

    char* ws = (char*)d_ws;
    size_t off = 0;
    auto carve = [&](size_t bytes) -> char* {
        char* p = ws + off;
        off += (bytes + 255) & ~(size_t)255;
        return p;
    };
    float* xf = (float*)carve(PK);
    uint*  xp = (uint*)carve(PK);
    uint*  ep = (uint*)carve(PK);
    char*  clu = carve(4 * PK);        // qp|kp|vtp|atp == FFN hidden (64 MiB)
    uint*  qp  = (uint*)clu;
    uint*  kp  = (uint*)(clu + PK);
    uint*  vtp = (uint*)(clu + 2 * PK);
    uint*  atp = (uint*)(clu + 3 * PK);
    uint*  hp  = (uint*)clu;
    float* yf = (float*)carve(PK);
    char*  scv = carve(PK);            // vp (pre-transpose V) == scores
    uint*  vp = (uint*)scv;
    float* scores = (float*)scv;
    uint*  pp = (uint*)carve(PK);
    uint*  wtp = (uint*)carve(PK);     // D*DFF u32 = 16 MiB max

    auto gemm = [&](const uint* Ap, const uint* Bp, float* Cf, uint* Cp,
                    const float* bias, float alpha, int gm, int gn, int gk,
                    long sA, long sB, long sC, int batch) {
        dim3 g(gn / 128, gm / 128, batch);
        gemm_sp<<<g, blk, 0, stream>>>(Ap, Bp, Cf, Cp, bias, alpha, gm, gn, gk, sA, sB, sC);
    };
    auto transp = [&](const float* W, int K, int N) {
        transpose_w<<<dim3(N / 32, K / 32), blk, 0, stream>>>(W, wtp, K, N);
    };

    cvt_pack<<<(M * D) / 1024, blk, 0, stream>>>(x_in, xp, M * D);
    cvt_pack<<<(M * D) / 1024, blk, 0, stream>>>(enc, ep, M * D);

    const long SM = (long)S * S;
    const long SD = (long)S * D;

    for (int i = 0; i < L; i++) {
        // ---- self-attention (causal) ----
        transp(Wq1 + (size_t)i * D * D, D, D);
        gemm(xp, wtp, nullptr, qp, nullptr, 1.f, M, D, D, 0, 0, 0, 1);
        transp(Wk1 + (size_t)i * D * D, D, D);
        gemm(xp, wtp, nullptr, kp, nullptr, 1.f, M, D, D, 0, 0, 0, 1);
        transp(Wv1 + (size_t)i * D * D, D, D);
        gemm(xp, wtp, nullptr, vp, nullptr, 1.f, M, D, D, 0, 0, 0, 1);
        vtrans<<<dim3(D / 32, S / 32, BATCH), blk, 0, stream>>>(vp, vtp);
        gemm(qp, kp, scores, nullptr, nullptr, 0.125f, S, S, D, SD, SD, SM, BATCH);
        softmax_rows<<<dim3(S, BATCH), blk, 0, stream>>>(scores, pp, 1);
        gemm(pp, vtp, nullptr, atp, nullptr, 1.f, S, D, S, SM, SD, SD, BATCH);
        transp(Wo1 + (size_t)i * D * D, D, D);
        gemm(atp, wtp, yf, nullptr, nullptr, 1.f, M, D, D, 0, 0, 0, 1);
        ln_res<<<M, blk, 0, stream>>>((i == 0) ? x_in : xf, yf,
                                      g1 + (size_t)i * D, b1 + (size_t)i * D, xf, xp);

        // ---- cross-attention (all visible) ----
        transp(Wq2 + (size_t)i * D * D, D, D);
        gemm(xp, wtp, nullptr, qp, nullptr, 1.f, M, D, D, 0, 0, 0, 1);
        transp(Wk2 + (size_t)i * D * D, D, D);
        gemm(ep, wtp, nullptr, kp, nullptr, 1.f, M, D, D, 0, 0, 0, 1);
        transp(Wv2 + (size_t)i * D * D, D, D);
        gemm(ep, wtp, nullptr, vp, nullptr, 1.f, M, D, D, 0, 0, 0, 1);
        vtrans<<<dim3(D / 32, S / 32, BATCH), blk, 0, stream>>>(vp, vtp);
        gemm(qp, kp, scores, nullptr, nullptr, 0.125f, S, S, D, SD, SD, SM, BATCH);
        softmax_rows<<<dim3(S, BATCH), blk, 0, stream>>>(scores, pp, 0);
        gemm(pp, vtp, nullptr, atp, nullptr, 1.f, S, D, S, SM, SD, SD, BATCH);
        transp(Wo2 + (size_t)i * D * D, D, D);
        gemm(atp, wtp, yf, nullptr, nullptr, 1.f, M, D, D, 0, 0, 0, 1);
        ln_res<<<M, blk, 0, stream>>>(xf, yf, g2 + (size_t)i * D, b2 + (size_t)i * D, xf, xp);

        // ---- feedforward ----
        transp(Wf1 + (size_t)i * D * DFF, D, DFF);
        gemm(xp, wtp, nullptr, hp, bf1 + (size_t)i * DFF, 1.f, M, DFF, D, 0, 0, 0, 1);
        transp(Wf2 + (size_t)i * DFF * D, DFF, D);
        gemm(hp, wtp, yf, nullptr, bf2 + (size_t)i * D, 1.f, M, D, DFF, 0, 0, 0, 1);
        float* lnout = (i == L - 1) ? (float*)d_out : xf;
        ln_res<<<M, blk, 0, stream>>>(xf, yf, g3 + (size_t)i * D, b3 + (size_t)i * D, lnout, xp);
    }
}

// Round 7
// 4795.234 us; speedup vs baseline: 2.4565x; 1.0623x over previous
//
#include <hip/hip_runtime.h>

#define L 6
#define D 1024
#define DFF 4096
#define BATCH 4
#define S 1024

typedef __attribute__((ext_vector_type(4))) float f32x4;
typedef __attribute__((ext_vector_type(8))) short short8;

__device__ __forceinline__ ushort f2bf(float f) {
    unsigned int u = __float_as_uint(f);
    u = u + 0x7FFF + ((u >> 16) & 1);
    return (ushort)(u >> 16);
}
__device__ __forceinline__ float bf2f(ushort u) {
    return __uint_as_float(((unsigned int)u) << 16);
}
__device__ __forceinline__ void gload16(const ushort* g, ushort* l) {
    __builtin_amdgcn_global_load_lds(
        (const __attribute__((address_space(1))) void*)g,
        (__attribute__((address_space(3))) void*)l, 16, 0, 0);
}

// ---------------- split f32 -> (hi, lo) bf16 planes ----------------
__global__ __launch_bounds__(256) void cvt_split(const float* __restrict__ in,
                                                 ushort* __restrict__ oh,
                                                 ushort* __restrict__ ol, int n) {
    int i = (blockIdx.x * 256 + threadIdx.x) * 4;
    if (i >= n) return;
    float4 v = *(const float4*)&in[i];
    ushort4 h, l;
    h.x = f2bf(v.x); l.x = f2bf(v.x - bf2f(h.x));
    h.y = f2bf(v.y); l.y = f2bf(v.y - bf2f(h.y));
    h.z = f2bf(v.z); l.z = f2bf(v.z - bf2f(h.z));
    h.w = f2bf(v.w); l.w = f2bf(v.w - bf2f(h.w));
    *(ushort4*)&oh[i] = h;
    *(ushort4*)&ol[i] = l;
}

// ------- transpose up to 3 weights [K,N] f32 -> stacked [z*N + n][K] h/l bf16 -------
__global__ __launch_bounds__(256) void transpose_w(const float* __restrict__ W0,
                                                   const float* __restrict__ W1,
                                                   const float* __restrict__ W2,
                                                   ushort* __restrict__ outh,
                                                   ushort* __restrict__ outl,
                                                   int K, int N) {
    const float* W = blockIdx.z == 0 ? W0 : (blockIdx.z == 1 ? W1 : W2);
    __shared__ float T[32][33];
    int n0 = blockIdx.x * 32, k0 = blockIdx.y * 32;
    int t = threadIdx.x;
    int r = t >> 3, c4 = (t & 7) * 4;
    float4 v = *(const float4*)&W[(size_t)(k0 + r) * N + n0 + c4];
    T[r][c4 + 0] = v.x; T[r][c4 + 1] = v.y; T[r][c4 + 2] = v.z; T[r][c4 + 3] = v.w;
    __syncthreads();
    float a0 = T[c4 + 0][r], a1 = T[c4 + 1][r], a2 = T[c4 + 2][r], a3 = T[c4 + 3][r];
    ushort4 h, l;
    h.x = f2bf(a0); l.x = f2bf(a0 - bf2f(h.x));
    h.y = f2bf(a1); l.y = f2bf(a1 - bf2f(h.y));
    h.z = f2bf(a2); l.z = f2bf(a2 - bf2f(h.z));
    h.w = f2bf(a3); l.w = f2bf(a3 - bf2f(h.w));
    size_t ob = ((size_t)blockIdx.z * N + n0 + r) * K + k0 + c4;
    *(ushort4*)&outh[ob] = h;
    *(ushort4*)&outl[ob] = l;
}

// ---------------- transpose V planes [b][s][3072-strided] -> [b][d][s] ----------------
__global__ __launch_bounds__(256) void vtrans(const ushort* __restrict__ inh,
                                              const ushort* __restrict__ inl,
                                              ushort* __restrict__ outh,
                                              ushort* __restrict__ outl,
                                              int ld_in, int col_off) {
    __shared__ ushort T[32][40];
    const int pz = blockIdx.z, b = pz >> 1;
    const ushort* in = (pz & 1) ? inl : inh;
    ushort* out = (pz & 1) ? outl : outh;
    const int d0 = blockIdx.x * 32, s0 = blockIdx.y * 32;
    const int t = threadIdx.x, r = t >> 3, c4 = (t & 7) * 4;
    ushort4 v = *(const ushort4*)&in[(size_t)(b * S + s0 + r) * ld_in + col_off + d0 + c4];
    T[r][c4 + 0] = v.x; T[r][c4 + 1] = v.y; T[r][c4 + 2] = v.z; T[r][c4 + 3] = v.w;
    __syncthreads();
    ushort4 o = {T[c4 + 0][r], T[c4 + 1][r], T[c4 + 2][r], T[c4 + 3][r]};
    *(ushort4*)&out[(size_t)(b * D + d0 + r) * S + s0 + c4] = o;
}

// ---------------- split-precision GEMM, global_load_lds staging ----------------
// C = alpha*(Ah+Al)[M,K] @ (Bh+Bl)[N,K]^T (+bias); 3 MFMA passes hh+hl+lh
__global__ __launch_bounds__(256) void gemm3(
    const ushort* __restrict__ Ah, const ushort* __restrict__ Al,
    const ushort* __restrict__ Bh, const ushort* __restrict__ Bl,
    float* __restrict__ Cf, ushort* __restrict__ Ch, ushort* __restrict__ Cl,
    const float* __restrict__ bias, float alpha,
    int M, int N, int K, int lda, int ldb, int ldc,
    long sA, long sB, long sC) {
    __shared__ ushort lds[4 * 128 * 64];
    ushort* Ash = lds;
    ushort* Asl = lds + 128 * 64;
    ushort* Bsh = lds + 2 * 128 * 64;
    ushort* Bsl = lds + 3 * 128 * 64;

    // XCD-aware swizzle (all launched grids have nblk % 8 == 0)
    const int gx = gridDim.x, gy = gridDim.y;
    int nblk = gx * gy * gridDim.z;
    int bid = (blockIdx.z * gy + blockIdx.y) * gx + blockIdx.x;
    if ((nblk & 7) == 0) bid = (bid & 7) * (nblk >> 3) + (bid >> 3);
    const int bx = bid % gx;
    int rem = bid / gx;
    const int by = rem % gy;
    const int z = rem / gy;

    const int bm = by * 128, bn = bx * 128;
    const ushort* A0 = Ah + (size_t)z * sA;
    const ushort* A1 = Al + (size_t)z * sA;
    const ushort* B0 = Bh + (size_t)z * sB;
    const ushort* B1 = Bl + (size_t)z * sB;
    const size_t coff = (size_t)z * sC;

    const int tid = threadIdx.x, lane = tid & 63;
    const int wid = tid >> 6, wr = wid >> 1, wc = wid & 1;
    const int lr = lane & 15, lg = lane >> 4;

    f32x4 acc[4][4] = {};
    const int NT = K >> 6;

    for (int kt = 0; kt < NT; kt++) {
        const int k0 = kt << 6;
        if (kt) __syncthreads();
#pragma unroll
        for (int c = 0; c < 4; c++) {
            const int idx = c * 256 + tid;
            const int row = idx >> 3, col = (idx & 7) * 8;
            const int lbase = (c * 256 + (tid & 192)) * 8;
            const size_t aoff = (size_t)(bm + row) * lda + k0 + col;
            const size_t boff = (size_t)(bn + row) * ldb + k0 + col;
            gload16(A0 + aoff, Ash + lbase);
            gload16(A1 + aoff, Asl + lbase);
            gload16(B0 + boff, Bsh + lbase);
            gload16(B1 + boff, Bsl + lbase);
        }
        asm volatile("s_waitcnt vmcnt(0)" ::: "memory");
        __syncthreads();
#pragma unroll
        for (int ks = 0; ks < 2; ks++) {
            short8 afh[4], afl[4], bfh[4], bfl[4];
#pragma unroll
            for (int i = 0; i < 4; i++) {
                const int ar = (wr * 64 + i * 16 + lr) * 64 + ks * 32 + lg * 8;
                const int br = (wc * 64 + i * 16 + lr) * 64 + ks * 32 + lg * 8;
                afh[i] = *(const short8*)&Ash[ar];
                afl[i] = *(const short8*)&Asl[ar];
                bfh[i] = *(const short8*)&Bsh[br];
                bfl[i] = *(const short8*)&Bsl[br];
            }
#pragma unroll
            for (int i = 0; i < 4; i++)
#pragma unroll
                for (int j = 0; j < 4; j++) {
                    acc[i][j] = __builtin_amdgcn_mfma_f32_16x16x32_bf16(afh[i], bfh[j], acc[i][j], 0, 0, 0);
                    acc[i][j] = __builtin_amdgcn_mfma_f32_16x16x32_bf16(afh[i], bfl[j], acc[i][j], 0, 0, 0);
                    acc[i][j] = __builtin_amdgcn_mfma_f32_16x16x32_bf16(afl[i], bfh[j], acc[i][j], 0, 0, 0);
                }
        }
    }
#pragma unroll
    for (int j = 0; j < 4; j++) {
        const int n = bn + wc * 64 + j * 16 + lr;
        const float bv = bias ? bias[n] : 0.f;
#pragma unroll
        for (int i = 0; i < 4; i++) {
#pragma unroll
            for (int r = 0; r < 4; r++) {
                const int m = bm + wr * 64 + i * 16 + lg * 4 + r;
                float v = acc[i][j][r] * alpha + bv;
                const size_t ci = coff + (size_t)m * ldc + n;
                if (Cf) Cf[ci] = v;
                if (Ch) {
                    ushort h = f2bf(v);
                    Ch[ci] = h;
                    Cl[ci] = f2bf(v - bf2f(h));
                }
            }
        }
    }
}

// ---------------- row softmax (f32 in, h/l bf16 planes out) ----------------
__global__ __launch_bounds__(256) void softmax_rows(const float* __restrict__ Sc,
                                                    ushort* __restrict__ Ph,
                                                    ushort* __restrict__ Pl, int causal) {
    __shared__ float red[4];
    int q = blockIdx.x, b = blockIdx.y;
    size_t base = ((size_t)b * S + q) * S;
    int valid = causal ? (q + 1) : S;
    int tid = threadIdx.x;
    float v[4];
    float mx = -3e38f;
#pragma unroll
    for (int j = 0; j < 4; j++) {
        int c = tid + j * 256;
        float x = Sc[base + c];
        v[j] = (c < valid) ? x : -3e38f;
        mx = fmaxf(mx, v[j]);
    }
    for (int o = 32; o; o >>= 1) mx = fmaxf(mx, __shfl_xor(mx, o));
    if ((tid & 63) == 0) red[tid >> 6] = mx;
    __syncthreads();
    mx = fmaxf(fmaxf(red[0], red[1]), fmaxf(red[2], red[3]));
    float s = 0.f;
#pragma unroll
    for (int j = 0; j < 4; j++) {
        int c = tid + j * 256;
        float e = (c < valid) ? __expf(v[j] - mx) : 0.f;
        v[j] = e;
        s += e;
    }
    for (int o = 32; o; o >>= 1) s += __shfl_xor(s, o);
    __syncthreads();
    if ((tid & 63) == 0) red[tid >> 6] = s;
    __syncthreads();
    s = red[0] + red[1] + red[2] + red[3];
    float inv = 1.0f / s;
#pragma unroll
    for (int j = 0; j < 4; j++) {
        int c = tid + j * 256;
        float p = v[j] * inv;
        ushort h = f2bf(p);
        Ph[base + c] = h;
        Pl[base + c] = f2bf(p - bf2f(h));
    }
}

// ---------------- residual + layernorm (f32 in, f32 + h/l planes out) ----------------
__global__ __launch_bounds__(256) void ln_res(const float* __restrict__ xin,
                                              const float* __restrict__ y,
                                              const float* __restrict__ g,
                                              const float* __restrict__ bta,
                                              float* __restrict__ xof,
                                              ushort* __restrict__ xh,
                                              ushort* __restrict__ xl) {
    __shared__ float red[4];
    int row = blockIdx.x;
    size_t base = (size_t)row * D;
    int tid = threadIdx.x;
    int c0 = tid * 4;
    float4 xv = *(const float4*)&xin[base + c0];
    float4 yv = *(const float4*)&y[base + c0];
    float t[4] = {xv.x + yv.x, xv.y + yv.y, xv.z + yv.z, xv.w + yv.w};
    float s = t[0] + t[1] + t[2] + t[3];
    for (int o = 32; o; o >>= 1) s += __shfl_xor(s, o);
    if ((tid & 63) == 0) red[tid >> 6] = s;
    __syncthreads();
    s = red[0] + red[1] + red[2] + red[3];
    float mean = s * (1.0f / D);
    float vs = 0.f;
#pragma unroll
    for (int j = 0; j < 4; j++) {
        float dd = t[j] - mean;
        vs += dd * dd;
    }
    for (int o = 32; o; o >>= 1) vs += __shfl_xor(vs, o);
    __syncthreads();
    if ((tid & 63) == 0) red[tid >> 6] = vs;
    __syncthreads();
    vs = red[0] + red[1] + red[2] + red[3];
    float inv = rsqrtf(vs * (1.0f / D) + 1e-5f);
    float4 gv = *(const float4*)&g[c0];
    float4 bv = *(const float4*)&bta[c0];
    float o0 = (t[0] - mean) * inv * gv.x + bv.x;
    float o1 = (t[1] - mean) * inv * gv.y + bv.y;
    float o2 = (t[2] - mean) * inv * gv.z + bv.z;
    float o3 = (t[3] - mean) * inv * gv.w + bv.w;
    float4 fo = {o0, o1, o2, o3};
    *(float4*)&xof[base + c0] = fo;
    ushort4 h, l;
    h.x = f2bf(o0); l.x = f2bf(o0 - bf2f(h.x));
    h.y = f2bf(o1); l.y = f2bf(o1 - bf2f(h.y));
    h.z = f2bf(o2); l.z = f2bf(o2 - bf2f(h.z));
    h.w = f2bf(o3); l.w = f2bf(o3 - bf2f(h.w));
    *(ushort4*)&xh[base + c0] = h;
    *(ushort4*)&xl[base + c0] = l;
}

__global__ __launch_bounds__(256) void fill_f32(float* out, float v, int n) {
    int i = (blockIdx.x * 256 + threadIdx.x) * 4;
    if (i >= n) return;
    float4 f = {v, v, v, v};
    *(float4*)&out[i] = f;
}

extern "C" void kernel_launch(void* const* d_in, const int* in_sizes, int n_in,
                              void* d_out, int out_size, void* d_ws, size_t ws_size,
                              hipStream_t stream) {
    dim3 blk(256);
    const int M = BATCH * S;  // 4096
    const int fill_blocks = (out_size / 4 + 255) / 256;

    int base = n_in - 18;
    bool layout_ok = (base >= 2) && (out_size == M * D) &&
                     (in_sizes[0] == M * D) && (in_sizes[1] == M * D) &&
                     (in_sizes[base] == L * D * D) && (in_sizes[base + 4] == L * D) &&
                     (in_sizes[base + 12] == L * D * DFF) && (in_sizes[base + 13] == L * DFF);
    if (!layout_ok) {
        fill_f32<<<fill_blocks, blk, 0, stream>>>((float*)d_out, 9000.f, out_size);
        return;
    }
    const float* x_in = (const float*)d_in[0];
    const float* enc  = (const float*)d_in[1];
    const float* Wq1 = (const float*)d_in[base + 0];
    const float* Wk1 = (const float*)d_in[base + 1];
    const float* Wv1 = (const float*)d_in[base + 2];
    const float* Wo1 = (const float*)d_in[base + 3];
    const float* g1  = (const float*)d_in[base + 4];
    const float* b1  = (const float*)d_in[base + 5];
    const float* Wq2 = (const float*)d_in[base + 6];
    const float* Wk2 = (const float*)d_in[base + 7];
    const float* Wv2 = (const float*)d_in[base + 8];
    const float* Wo2 = (const float*)d_in[base + 9];
    const float* g2  = (const float*)d_in[base + 10];
    const float* b2  = (const float*)d_in[base + 11];
    const float* Wf1 = (const float*)d_in[base + 12];
    const float* bf1 = (const float*)d_in[base + 13];
    const float* Wf2 = (const float*)d_in[base + 14];
    const float* bf2 = (const float*)d_in[base + 15];
    const float* g3  = (const float*)d_in[base + 16];
    const float* b3  = (const float*)d_in[base + 17];

    const size_t PL = (size_t)M * D * 2;   // 8 MiB bf16 plane
    const size_t required = 22 * PL;       // 176 MiB (same as round 6)
    if (ws_size < required) {
        fill_f32<<<fill_blocks, blk, 0, stream>>>((float*)d_out, 500.f, out_size);
        return;
    }

    char* ws = (char*)d_ws;
    size_t off = 0;
    auto carve = [&](size_t bytes) -> char* {
        char* p = ws + off;
        off += (bytes + 255) & ~(size_t)255;
        return p;
    };
    float*  xf = (float*)carve(2 * PL);
    ushort* xh = (ushort*)carve(PL);
    ushort* xl = (ushort*)carve(PL);
    ushort* eh = (ushort*)carve(PL);
    ushort* el = (ushort*)carve(PL);
    char*   clu = carve(10 * PL);
    ushort* qkvh = (ushort*)clu;                 // 3 PL (4096 x 3072)
    ushort* qkvl = (ushort*)(clu + 3 * PL);      // 3 PL
    ushort* vth  = (ushort*)(clu + 6 * PL);      // [b][d][s]
    ushort* vtl  = (ushort*)(clu + 7 * PL);
    float*  scores = (float*)(clu + 8 * PL);     // 2 PL f32, aliases at-planes
    ushort* ath  = (ushort*)(clu + 8 * PL);
    ushort* atl  = (ushort*)(clu + 9 * PL);
    ushort* hph  = (ushort*)clu;                 // FFN hidden aliases qkv+vt (4 PL each)
    ushort* hpl  = (ushort*)(clu + 4 * PL);
    ushort* ph = (ushort*)carve(PL);
    ushort* pl_ = (ushort*)carve(PL);
    float*  yf = (float*)carve(2 * PL);
    ushort* wth = (ushort*)carve(PL);
    ushort* wtl = (ushort*)carve(PL);

    auto gemm = [&](const ushort* Ah, const ushort* Al, const ushort* Bh, const ushort* Bl,
                    float* Cf, ushort* Ch, ushort* Cl, const float* bias, float alpha,
                    int gm, int gn, int gk, int lda, int ldb, int ldc,
                    long sA, long sB, long sC, int batch) {
        dim3 g(gn / 128, gm / 128, batch);
        gemm3<<<g, blk, 0, stream>>>(Ah, Al, Bh, Bl, Cf, Ch, Cl, bias, alpha,
                                     gm, gn, gk, lda, ldb, ldc, sA, sB, sC);
    };
    auto transp = [&](const float* W0, const float* W1, const float* W2, int nw, int K, int N) {
        transpose_w<<<dim3(N / 32, K / 32, nw), blk, 0, stream>>>(W0, W1, W2, wth, wtl, K, N);
    };

    cvt_split<<<(M * D) / 1024, blk, 0, stream>>>(x_in, xh, xl, M * D);
    cvt_split<<<(M * D) / 1024, blk, 0, stream>>>(enc, eh, el, M * D);

    const long SM = (long)S * S;
    const long S3 = (long)S * 3072;
    const long SD = (long)S * D;

    for (int i = 0; i < L; i++) {
        size_t wo = (size_t)i * D * D;
        // ---- self-attention (causal) ----
        transp(Wq1 + wo, Wk1 + wo, Wv1 + wo, 3, D, D);
        gemm(xh, xl, wth, wtl, nullptr, qkvh, qkvl, nullptr, 1.f,
             M, 3 * D, D, D, D, 3 * D, 0, 0, 0, 1);
        vtrans<<<dim3(D / 32, S / 32, 2 * BATCH), blk, 0, stream>>>(qkvh, qkvl, vth, vtl, 3 * D, 2 * D);
        gemm(qkvh, qkvl, qkvh + D, qkvl + D, scores, nullptr, nullptr, nullptr, 0.125f,
             S, S, D, 3 * D, 3 * D, S, S3, S3, SM, BATCH);
        softmax_rows<<<dim3(S, BATCH), blk, 0, stream>>>(scores, ph, pl_, 1);
        gemm(ph, pl_, vth, vtl, nullptr, ath, atl, nullptr, 1.f,
             S, D, S, S, S, D, SM, SD, SD, BATCH);
        transp(Wo1 + wo, nullptr, nullptr, 1, D, D);
        gemm(ath, atl, wth, wtl, yf, nullptr, nullptr, nullptr, 1.f,
             M, D, D, D, D, D, 0, 0, 0, 1);
        ln_res<<<M, blk, 0, stream>>>((i == 0) ? x_in : xf, yf,
                                      g1 + (size_t)i * D, b1 + (size_t)i * D, xf, xh, xl);

        // ---- cross-attention (all visible) ----
        transp(Wq2 + wo, nullptr, nullptr, 1, D, D);
        gemm(xh, xl, wth, wtl, nullptr, qkvh, qkvl, nullptr, 1.f,
             M, D, D, D, D, 3 * D, 0, 0, 0, 1);
        transp(Wk2 + wo, Wv2 + wo, nullptr, 2, D, D);
        gemm(eh, el, wth, wtl, nullptr, qkvh + D, qkvl + D, nullptr, 1.f,
             M, 2 * D, D, D, D, 3 * D, 0, 0, 0, 1);
        vtrans<<<dim3(D / 32, S / 32, 2 * BATCH), blk, 0, stream>>>(qkvh, qkvl, vth, vtl, 3 * D, 2 * D);
        gemm(qkvh, qkvl, qkvh + D, qkvl + D, scores, nullptr, nullptr, nullptr, 0.125f,
             S, S, D, 3 * D, 3 * D, S, S3, S3, SM, BATCH);
        softmax_rows<<<dim3(S, BATCH), blk, 0, stream>>>(scores, ph, pl_, 0);
        gemm(ph, pl_, vth, vtl, nullptr, ath, atl, nullptr, 1.f,
             S, D, S, S, S, D, SM, SD, SD, BATCH);
        transp(Wo2 + wo, nullptr, nullptr, 1, D, D);
        gemm(ath, atl, wth, wtl, yf, nullptr, nullptr, nullptr, 1.f,
             M, D, D, D, D, D, 0, 0, 0, 1);
        ln_res<<<M, blk, 0, stream>>>(xf, yf, g2 + (size_t)i * D, b2 + (size_t)i * D, xf, xh, xl);

        // ---- feedforward ----
        transp(Wf1 + (size_t)i * D * DFF, nullptr, nullptr, 1, D, DFF);
        gemm(xh, xl, wth, wtl, nullptr, hph, hpl, bf1 + (size_t)i * DFF, 1.f,
             M, DFF, D, D, D, DFF, 0, 0, 0, 1);
        transp(Wf2 + (size_t)i * DFF * D, nullptr, nullptr, 1, DFF, D);
        gemm(hph, hpl, wth, wtl, yf, nullptr, nullptr, bf2 + (size_t)i * D, 1.f,
             M, D, DFF, DFF, DFF, D, 0, 0, 0, 1);
        float* lnout = (i == L - 1) ? (float*)d_out : xf;
        ln_res<<<M, blk, 0, stream>>>(xf, yf, g3 + (size_t)i * D, b3 + (size_t)i * D, lnout, xh, xl);
    }
}

// Round 8
// 4307.707 us; speedup vs baseline: 2.7345x; 1.1132x over previous
//
#include <hip/hip_runtime.h>

#define L 6
#define D 1024
#define DFF 4096
#define BATCH 4
#define S 1024

typedef __attribute__((ext_vector_type(4))) float f32x4;
typedef __attribute__((ext_vector_type(8))) short short8;

__device__ __forceinline__ ushort f2bf(float f) {
    unsigned int u = __float_as_uint(f);
    u = u + 0x7FFF + ((u >> 16) & 1);
    return (ushort)(u >> 16);
}
__device__ __forceinline__ float bf2f(ushort u) {
    return __uint_as_float(((unsigned int)u) << 16);
}
__device__ __forceinline__ void gload16(const ushort* g, ushort* l) {
    __builtin_amdgcn_global_load_lds(
        (const __attribute__((address_space(1))) void*)g,
        (__attribute__((address_space(3))) void*)l, 16, 0, 0);
}

// ---------------- split f32 -> (hi, lo) bf16 planes ----------------
__global__ __launch_bounds__(256) void cvt_split(const float* __restrict__ in,
                                                 ushort* __restrict__ oh,
                                                 ushort* __restrict__ ol, int n) {
    int i = (blockIdx.x * 256 + threadIdx.x) * 4;
    if (i >= n) return;
    float4 v = *(const float4*)&in[i];
    ushort4 h, l;
    h.x = f2bf(v.x); l.x = f2bf(v.x - bf2f(h.x));
    h.y = f2bf(v.y); l.y = f2bf(v.y - bf2f(h.y));
    h.z = f2bf(v.z); l.z = f2bf(v.z - bf2f(h.z));
    h.w = f2bf(v.w); l.w = f2bf(v.w - bf2f(h.w));
    *(ushort4*)&oh[i] = h;
    *(ushort4*)&ol[i] = l;
}

// ------- transpose up to 3 weights [K,N] f32 -> stacked [z*N + n][K] h/l bf16 -------
__global__ __launch_bounds__(256) void transpose_w(const float* __restrict__ W0,
                                                   const float* __restrict__ W1,
                                                   const float* __restrict__ W2,
                                                   ushort* __restrict__ outh,
                                                   ushort* __restrict__ outl,
                                                   int K, int N) {
    const float* W = blockIdx.z == 0 ? W0 : (blockIdx.z == 1 ? W1 : W2);
    __shared__ float T[32][33];
    int n0 = blockIdx.x * 32, k0 = blockIdx.y * 32;
    int t = threadIdx.x;
    int r = t >> 3, c4 = (t & 7) * 4;
    float4 v = *(const float4*)&W[(size_t)(k0 + r) * N + n0 + c4];
    T[r][c4 + 0] = v.x; T[r][c4 + 1] = v.y; T[r][c4 + 2] = v.z; T[r][c4 + 3] = v.w;
    __syncthreads();
    float a0 = T[c4 + 0][r], a1 = T[c4 + 1][r], a2 = T[c4 + 2][r], a3 = T[c4 + 3][r];
    ushort4 h, l;
    h.x = f2bf(a0); l.x = f2bf(a0 - bf2f(h.x));
    h.y = f2bf(a1); l.y = f2bf(a1 - bf2f(h.y));
    h.z = f2bf(a2); l.z = f2bf(a2 - bf2f(h.z));
    h.w = f2bf(a3); l.w = f2bf(a3 - bf2f(h.w));
    size_t ob = ((size_t)blockIdx.z * N + n0 + r) * K + k0 + c4;
    *(ushort4*)&outh[ob] = h;
    *(ushort4*)&outl[ob] = l;
}

// ---------------- transpose V planes [b][s][3072-strided] -> [b][d][s] ----------------
__global__ __launch_bounds__(256) void vtrans(const ushort* __restrict__ inh,
                                              const ushort* __restrict__ inl,
                                              ushort* __restrict__ outh,
                                              ushort* __restrict__ outl,
                                              int ld_in, int col_off) {
    __shared__ ushort T[32][40];
    const int pz = blockIdx.z, b = pz >> 1;
    const ushort* in = (pz & 1) ? inl : inh;
    ushort* out = (pz & 1) ? outl : outh;
    const int d0 = blockIdx.x * 32, s0 = blockIdx.y * 32;
    const int t = threadIdx.x, r = t >> 3, c4 = (t & 7) * 4;
    ushort4 v = *(const ushort4*)&in[(size_t)(b * S + s0 + r) * ld_in + col_off + d0 + c4];
    T[r][c4 + 0] = v.x; T[r][c4 + 1] = v.y; T[r][c4 + 2] = v.z; T[r][c4 + 3] = v.w;
    __syncthreads();
    ushort4 o = {T[c4 + 0][r], T[c4 + 1][r], T[c4 + 2][r], T[c4 + 3][r]};
    *(ushort4*)&out[(size_t)(b * D + d0 + r) * S + s0 + c4] = o;
}

// ---------------- split-precision GEMM, global_load_lds + XOR-swizzled LDS ----------------
// C = alpha*(Ah+Al)[M,K] @ (Bh+Bl)[N,K]^T (+bias); 3 MFMA passes hh+hl+lh
// LDS tile [128][64] bf16 linear; slot s (8 elems) of row r stored at slot s^(r&7).
// Staging pre-swizzles the GLOBAL source column; reads apply the same XOR (rule #21).
__global__ __launch_bounds__(256) void gemm3(
    const ushort* __restrict__ Ah, const ushort* __restrict__ Al,
    const ushort* __restrict__ Bh, const ushort* __restrict__ Bl,
    float* __restrict__ Cf, ushort* __restrict__ Ch, ushort* __restrict__ Cl,
    const float* __restrict__ bias, float alpha,
    int M, int N, int K, int lda, int ldb, int ldc,
    long sA, long sB, long sC) {
    __shared__ ushort lds[4 * 128 * 64];
    ushort* Ash = lds;
    ushort* Asl = lds + 128 * 64;
    ushort* Bsh = lds + 2 * 128 * 64;
    ushort* Bsl = lds + 3 * 128 * 64;

    // XCD-aware swizzle (all launched grids have nblk % 8 == 0)
    const int gx = gridDim.x, gy = gridDim.y;
    int nblk = gx * gy * gridDim.z;
    int bid = (blockIdx.z * gy + blockIdx.y) * gx + blockIdx.x;
    if ((nblk & 7) == 0) bid = (bid & 7) * (nblk >> 3) + (bid >> 3);
    const int bx = bid % gx;
    int rem = bid / gx;
    const int by = rem % gy;
    const int z = rem / gy;

    const int bm = by * 128, bn = bx * 128;
    const ushort* A0 = Ah + (size_t)z * sA;
    const ushort* A1 = Al + (size_t)z * sA;
    const ushort* B0 = Bh + (size_t)z * sB;
    const ushort* B1 = Bl + (size_t)z * sB;
    const size_t coff = (size_t)z * sC;

    const int tid = threadIdx.x, lane = tid & 63;
    const int wid = tid >> 6, wr = wid >> 1, wc = wid & 1;
    const int lr = lane & 15, lg = lane >> 4;

    f32x4 acc[4][4] = {};
    const int NT = K >> 6;

    for (int kt = 0; kt < NT; kt++) {
        const int k0 = kt << 6;
        if (kt) __syncthreads();
#pragma unroll
        for (int c = 0; c < 4; c++) {
            const int idx = c * 256 + tid;
            const int row = idx >> 3;
            // pre-swizzled global source column: srcSlot = ldsSlot ^ (row&7)
            const int col = (((idx & 7) ^ (row & 7)) * 8);
            const int lbase = (c * 256 + (tid & 192)) * 8;  // linear LDS dest
            const size_t aoff = (size_t)(bm + row) * lda + k0 + col;
            const size_t boff = (size_t)(bn + row) * ldb + k0 + col;
            gload16(A0 + aoff, Ash + lbase);
            gload16(A1 + aoff, Asl + lbase);
            gload16(B0 + boff, Bsh + lbase);
            gload16(B1 + boff, Bsl + lbase);
        }
        asm volatile("s_waitcnt vmcnt(0)" ::: "memory");
        __syncthreads();
#pragma unroll
        for (int ks = 0; ks < 2; ks++) {
            short8 afh[4], afl[4], bfh[4], bfl[4];
#pragma unroll
            for (int i = 0; i < 4; i++) {
                const int arow = wr * 64 + i * 16 + lr;
                const int brow = wc * 64 + i * 16 + lr;
                const int ar = arow * 64 + ((ks * 4 + lg) ^ (arow & 7)) * 8;
                const int br = brow * 64 + ((ks * 4 + lg) ^ (brow & 7)) * 8;
                afh[i] = *(const short8*)&Ash[ar];
                afl[i] = *(const short8*)&Asl[ar];
                bfh[i] = *(const short8*)&Bsh[br];
                bfl[i] = *(const short8*)&Bsl[br];
            }
#pragma unroll
            for (int i = 0; i < 4; i++)
#pragma unroll
                for (int j = 0; j < 4; j++) {
                    acc[i][j] = __builtin_amdgcn_mfma_f32_16x16x32_bf16(afh[i], bfh[j], acc[i][j], 0, 0, 0);
                    acc[i][j] = __builtin_amdgcn_mfma_f32_16x16x32_bf16(afh[i], bfl[j], acc[i][j], 0, 0, 0);
                    acc[i][j] = __builtin_amdgcn_mfma_f32_16x16x32_bf16(afl[i], bfh[j], acc[i][j], 0, 0, 0);
                }
        }
    }
#pragma unroll
    for (int j = 0; j < 4; j++) {
        const int n = bn + wc * 64 + j * 16 + lr;
        const float bv = bias ? bias[n] : 0.f;
#pragma unroll
        for (int i = 0; i < 4; i++) {
#pragma unroll
            for (int r = 0; r < 4; r++) {
                const int m = bm + wr * 64 + i * 16 + lg * 4 + r;
                float v = acc[i][j][r] * alpha + bv;
                const size_t ci = coff + (size_t)m * ldc + n;
                if (Cf) Cf[ci] = v;
                if (Ch) {
                    ushort h = f2bf(v);
                    Ch[ci] = h;
                    Cl[ci] = f2bf(v - bf2f(h));
                }
            }
        }
    }
}

// ---------------- row softmax (f32 in, h/l bf16 planes out) ----------------
__global__ __launch_bounds__(256) void softmax_rows(const float* __restrict__ Sc,
                                                    ushort* __restrict__ Ph,
                                                    ushort* __restrict__ Pl, int causal) {
    __shared__ float red[4];
    int q = blockIdx.x, b = blockIdx.y;
    size_t base = ((size_t)b * S + q) * S;
    int valid = causal ? (q + 1) : S;
    int tid = threadIdx.x;
    float v[4];
    float mx = -3e38f;
#pragma unroll
    for (int j = 0; j < 4; j++) {
        int c = tid + j * 256;
        float x = Sc[base + c];
        v[j] = (c < valid) ? x : -3e38f;
        mx = fmaxf(mx, v[j]);
    }
    for (int o = 32; o; o >>= 1) mx = fmaxf(mx, __shfl_xor(mx, o));
    if ((tid & 63) == 0) red[tid >> 6] = mx;
    __syncthreads();
    mx = fmaxf(fmaxf(red[0], red[1]), fmaxf(red[2], red[3]));
    float s = 0.f;
#pragma unroll
    for (int j = 0; j < 4; j++) {
        int c = tid + j * 256;
        float e = (c < valid) ? __expf(v[j] - mx) : 0.f;
        v[j] = e;
        s += e;
    }
    for (int o = 32; o; o >>= 1) s += __shfl_xor(s, o);
    __syncthreads();
    if ((tid & 63) == 0) red[tid >> 6] = s;
    __syncthreads();
    s = red[0] + red[1] + red[2] + red[3];
    float inv = 1.0f / s;
#pragma unroll
    for (int j = 0; j < 4; j++) {
        int c = tid + j * 256;
        float p = v[j] * inv;
        ushort h = f2bf(p);
        Ph[base + c] = h;
        Pl[base + c] = f2bf(p - bf2f(h));
    }
}

// ---------------- residual + layernorm (f32 in, f32 + h/l planes out) ----------------
__global__ __launch_bounds__(256) void ln_res(const float* __restrict__ xin,
                                              const float* __restrict__ y,
                                              const float* __restrict__ g,
                                              const float* __restrict__ bta,
                                              float* __restrict__ xof,
                                              ushort* __restrict__ xh,
                                              ushort* __restrict__ xl) {
    __shared__ float red[4];
    int row = blockIdx.x;
    size_t base = (size_t)row * D;
    int tid = threadIdx.x;
    int c0 = tid * 4;
    float4 xv = *(const float4*)&xin[base + c0];
    float4 yv = *(const float4*)&y[base + c0];
    float t[4] = {xv.x + yv.x, xv.y + yv.y, xv.z + yv.z, xv.w + yv.w};
    float s = t[0] + t[1] + t[2] + t[3];
    for (int o = 32; o; o >>= 1) s += __shfl_xor(s, o);
    if ((tid & 63) == 0) red[tid >> 6] = s;
    __syncthreads();
    s = red[0] + red[1] + red[2] + red[3];
    float mean = s * (1.0f / D);
    float vs = 0.f;
#pragma unroll
    for (int j = 0; j < 4; j++) {
        float dd = t[j] - mean;
        vs += dd * dd;
    }
    for (int o = 32; o; o >>= 1) vs += __shfl_xor(vs, o);
    __syncthreads();
    if ((tid & 63) == 0) red[tid >> 6] = vs;
    __syncthreads();
    vs = red[0] + red[1] + red[2] + red[3];
    float inv = rsqrtf(vs * (1.0f / D) + 1e-5f);
    float4 gv = *(const float4*)&g[c0];
    float4 bv = *(const float4*)&bta[c0];
    float o0 = (t[0] - mean) * inv * gv.x + bv.x;
    float o1 = (t[1] - mean) * inv * gv.y + bv.y;
    float o2 = (t[2] - mean) * inv * gv.z + bv.z;
    float o3 = (t[3] - mean) * inv * gv.w + bv.w;
    float4 fo = {o0, o1, o2, o3};
    *(float4*)&xof[base + c0] = fo;
    ushort4 h, l;
    h.x = f2bf(o0); l.x = f2bf(o0 - bf2f(h.x));
    h.y = f2bf(o1); l.y = f2bf(o1 - bf2f(h.y));
    h.z = f2bf(o2); l.z = f2bf(o2 - bf2f(h.z));
    h.w = f2bf(o3); l.w = f2bf(o3 - bf2f(h.w));
    *(ushort4*)&xh[base + c0] = h;
    *(ushort4*)&xl[base + c0] = l;
}

__global__ __launch_bounds__(256) void fill_f32(float* out, float v, int n) {
    int i = (blockIdx.x * 256 + threadIdx.x) * 4;
    if (i >= n) return;
    float4 f = {v, v, v, v};
    *(float4*)&out[i] = f;
}

extern "C" void kernel_launch(void* const* d_in, const int* in_sizes, int n_in,
                              void* d_out, int out_size, void* d_ws, size_t ws_size,
                              hipStream_t stream) {
    dim3 blk(256);
    const int M = BATCH * S;  // 4096
    const int fill_blocks = (out_size / 4 + 255) / 256;

    int base = n_in - 18;
    bool layout_ok = (base >= 2) && (out_size == M * D) &&
                     (in_sizes[0] == M * D) && (in_sizes[1] == M * D) &&
                     (in_sizes[base] == L * D * D) && (in_sizes[base + 4] == L * D) &&
                     (in_sizes[base + 12] == L * D * DFF) && (in_sizes[base + 13] == L * DFF);
    if (!layout_ok) {
        fill_f32<<<fill_blocks, blk, 0, stream>>>((float*)d_out, 9000.f, out_size);
        return;
    }
    const float* x_in = (const float*)d_in[0];
    const float* enc  = (const float*)d_in[1];
    const float* Wq1 = (const float*)d_in[base + 0];
    const float* Wk1 = (const float*)d_in[base + 1];
    const float* Wv1 = (const float*)d_in[base + 2];
    const float* Wo1 = (const float*)d_in[base + 3];
    const float* g1  = (const float*)d_in[base + 4];
    const float* b1  = (const float*)d_in[base + 5];
    const float* Wq2 = (const float*)d_in[base + 6];
    const float* Wk2 = (const float*)d_in[base + 7];
    const float* Wv2 = (const float*)d_in[base + 8];
    const float* Wo2 = (const float*)d_in[base + 9];
    const float* g2  = (const float*)d_in[base + 10];
    const float* b2  = (const float*)d_in[base + 11];
    const float* Wf1 = (const float*)d_in[base + 12];
    const float* bf1 = (const float*)d_in[base + 13];
    const float* Wf2 = (const float*)d_in[base + 14];
    const float* bf2 = (const float*)d_in[base + 15];
    const float* g3  = (const float*)d_in[base + 16];
    const float* b3  = (const float*)d_in[base + 17];

    const size_t PL = (size_t)M * D * 2;   // 8 MiB bf16 plane
    const size_t required = 22 * PL;       // 176 MiB
    if (ws_size < required) {
        fill_f32<<<fill_blocks, blk, 0, stream>>>((float*)d_out, 500.f, out_size);
        return;
    }

    char* ws = (char*)d_ws;
    size_t off = 0;
    auto carve = [&](size_t bytes) -> char* {
        char* p = ws + off;
        off += (bytes + 255) & ~(size_t)255;
        return p;
    };
    float*  xf = (float*)carve(2 * PL);
    ushort* xh = (ushort*)carve(PL);
    ushort* xl = (ushort*)carve(PL);
    ushort* eh = (ushort*)carve(PL);
    ushort* el = (ushort*)carve(PL);
    char*   clu = carve(10 * PL);
    ushort* qkvh = (ushort*)clu;                 // 3 PL (4096 x 3072)
    ushort* qkvl = (ushort*)(clu + 3 * PL);      // 3 PL
    ushort* vth  = (ushort*)(clu + 6 * PL);      // [b][d][s]
    ushort* vtl  = (ushort*)(clu + 7 * PL);
    float*  scores = (float*)(clu + 8 * PL);     // 2 PL f32, aliases at-planes
    ushort* ath  = (ushort*)(clu + 8 * PL);
    ushort* atl  = (ushort*)(clu + 9 * PL);
    ushort* hph  = (ushort*)clu;                 // FFN hidden aliases qkv+vt (4 PL each)
    ushort* hpl  = (ushort*)(clu + 4 * PL);
    ushort* ph = (ushort*)carve(PL);
    ushort* pl_ = (ushort*)carve(PL);
    float*  yf = (float*)carve(2 * PL);
    ushort* wth = (ushort*)carve(PL);
    ushort* wtl = (ushort*)carve(PL);

    auto gemm = [&](const ushort* Ah, const ushort* Al, const ushort* Bh, const ushort* Bl,
                    float* Cf, ushort* Ch, ushort* Cl, const float* bias, float alpha,
                    int gm, int gn, int gk, int lda, int ldb, int ldc,
                    long sA, long sB, long sC, int batch) {
        dim3 g(gn / 128, gm / 128, batch);
        gemm3<<<g, blk, 0, stream>>>(Ah, Al, Bh, Bl, Cf, Ch, Cl, bias, alpha,
                                     gm, gn, gk, lda, ldb, ldc, sA, sB, sC);
    };
    auto transp = [&](const float* W0, const float* W1, const float* W2, int nw, int K, int N) {
        transpose_w<<<dim3(N / 32, K / 32, nw), blk, 0, stream>>>(W0, W1, W2, wth, wtl, K, N);
    };

    cvt_split<<<(M * D) / 1024, blk, 0, stream>>>(x_in, xh, xl, M * D);
    cvt_split<<<(M * D) / 1024, blk, 0, stream>>>(enc, eh, el, M * D);

    const long SM = (long)S * S;
    const long S3 = (long)S * 3072;
    const long SD = (long)S * D;

    for (int i = 0; i < L; i++) {
        size_t wo = (size_t)i * D * D;
        // ---- self-attention (causal) ----
        transp(Wq1 + wo, Wk1 + wo, Wv1 + wo, 3, D, D);
        gemm(xh, xl, wth, wtl, nullptr, qkvh, qkvl, nullptr, 1.f,
             M, 3 * D, D, D, D, 3 * D, 0, 0, 0, 1);
        vtrans<<<dim3(D / 32, S / 32, 2 * BATCH), blk, 0, stream>>>(qkvh, qkvl, vth, vtl, 3 * D, 2 * D);
        gemm(qkvh, qkvl, qkvh + D, qkvl + D, scores, nullptr, nullptr, nullptr, 0.125f,
             S, S, D, 3 * D, 3 * D, S, S3, S3, SM, BATCH);
        softmax_rows<<<dim3(S, BATCH), blk, 0, stream>>>(scores, ph, pl_, 1);
        gemm(ph, pl_, vth, vtl, nullptr, ath, atl, nullptr, 1.f,
             S, D, S, S, S, D, SM, SD, SD, BATCH);
        transp(Wo1 + wo, nullptr, nullptr, 1, D, D);
        gemm(ath, atl, wth, wtl, yf, nullptr, nullptr, nullptr, 1.f,
             M, D, D, D, D, D, 0, 0, 0, 1);
        ln_res<<<M, blk, 0, stream>>>((i == 0) ? x_in : xf, yf,
                                      g1 + (size_t)i * D, b1 + (size_t)i * D, xf, xh, xl);

        // ---- cross-attention (all visible) ----
        transp(Wq2 + wo, nullptr, nullptr, 1, D, D);
        gemm(xh, xl, wth, wtl, nullptr, qkvh, qkvl, nullptr, 1.f,
             M, D, D, D, D, 3 * D, 0, 0, 0, 1);
        transp(Wk2 + wo, Wv2 + wo, nullptr, 2, D, D);
        gemm(eh, el, wth, wtl, nullptr, qkvh + D, qkvl + D, nullptr, 1.f,
             M, 2 * D, D, D, D, 3 * D, 0, 0, 0, 1);
        vtrans<<<dim3(D / 32, S / 32, 2 * BATCH), blk, 0, stream>>>(qkvh, qkvl, vth, vtl, 3 * D, 2 * D);
        gemm(qkvh, qkvl, qkvh + D, qkvl + D, scores, nullptr, nullptr, nullptr, 0.125f,
             S, S, D, 3 * D, 3 * D, S, S3, S3, SM, BATCH);
        softmax_rows<<<dim3(S, BATCH), blk, 0, stream>>>(scores, ph, pl_, 0);
        gemm(ph, pl_, vth, vtl, nullptr, ath, atl, nullptr, 1.f,
             S, D, S, S, S, D, SM, SD, SD, BATCH);
        transp(Wo2 + wo, nullptr, nullptr, 1, D, D);
        gemm(ath, atl, wth, wtl, yf, nullptr, nullptr, nullptr, 1.f,
             M, D, D, D, D, D, 0, 0, 0, 1);
        ln_res<<<M, blk, 0, stream>>>(xf, yf, g2 + (size_t)i * D, b2 + (size_t)i * D, xf, xh, xl);

        // ---- feedforward ----
        transp(Wf1 + (size_t)i * D * DFF, nullptr, nullptr, 1, D, DFF);
        gemm(xh, xl, wth, wtl, nullptr, hph, hpl, bf1 + (size_t)i * DFF, 1.f,
             M, DFF, D, D, D, DFF, 0, 0, 0, 1);
        transp(Wf2 + (size_t)i * DFF * D, nullptr, nullptr, 1, DFF, D);
        gemm(hph, hpl, wth, wtl, yf, nullptr, nullptr, bf2 + (size_t)i * D, 1.f,
             M, D, DFF, DFF, DFF, D, 0, 0, 0, 1);
        float* lnout = (i == L - 1) ? (float*)d_out : xf;
        ln_res<<<M, blk, 0, stream>>>(xf, yf, g3 + (size_t)i * D, b3 + (size_t)i * D, lnout, xh, xl);
    }
}